// Round 1
// baseline (204.883 us; speedup 1.0000x reference)
//
#include <hip/hip_runtime.h>

// Problem constants (fixed by the reference file)
#define SEQ         3456
#define DHEAD       32
#define FPT         216        // feats_per_t
#define WLEN        8          // window_len
#define NT          (SEQ/FPT)  // 16 time blocks
#define IMG_START   20         // FPT - img_feat_size(196)
#define JOINT_START 4          // IMG_START - act_size(16)
#define PROPRIO     4          // 2+1+1

// Mask rules derived from eye_mask():
//  same-t block (kv_t == q_t): all visible except (q_img && kv_img)
//  past block (q_t-7 <= kv_t < q_t): only kv_m < 20 can be visible;
//    kv_m == 4 (proprio) masked; kv_m in [4,20) masked if q is joint.
//    => vis_past = (j < 4) || (j >= 5 && !q_joint)

__global__ __launch_bounds__(256, 2)
void eye_attn_kernel(const float* __restrict__ q,
                     const float* __restrict__ k,
                     const float* __restrict__ v,
                     float* __restrict__ out) {
    const int t   = blockIdx.x;   // time block
    const int bh  = blockIdx.y;   // fused batch*head
    const int tid = threadIdx.x;

    __shared__ float Kl[FPT * DHEAD];   // 27.6 KB
    __shared__ float Vl[FPT * DHEAD];   // 27.6 KB

    const size_t base = (size_t)bh * SEQ * DHEAD;

    const int  qm      = tid;               // query index within the block
    const bool active  = qm < FPT;
    const bool q_img   = qm >= IMG_START;
    const bool q_joint = (qm >= JOINT_START) && (qm < IMG_START);

    float4 qr[8];
    float4 acc[8];
    float  l = 0.f;
    if (active) {
        const float* qp = q + base + (size_t)(t * FPT + qm) * DHEAD;
        #pragma unroll
        for (int i = 0; i < 8; ++i) {
            qr[i]  = ((const float4*)qp)[i];
            acc[i] = make_float4(0.f, 0.f, 0.f, 0.f);
        }
    }
    const float scale = 0.17677669529663687f;  // 1/sqrt(32)

    const int kb0 = (t >= WLEN - 1) ? t - (WLEN - 1) : 0;
    for (int kb = kb0; kb <= t; ++kb) {
        const bool same = (kb == t);
        const int  rows = same ? FPT : IMG_START;   // 216 or 20

        // --- stage K,V rows of block kb into LDS (coalesced float4) ---
        const float* kp = k + base + (size_t)kb * FPT * DHEAD;
        const float* vp = v + base + (size_t)kb * FPT * DHEAD;
        const int nf4 = rows * DHEAD / 4;           // 1728 or 160
        for (int i = tid; i < nf4; i += 256) {
            ((float4*)Kl)[i] = ((const float4*)kp)[i];
            ((float4*)Vl)[i] = ((const float4*)vp)[i];
        }
        __syncthreads();

        if (active) {
            // img queries see only the first 20 keys of their own block
            const int jmax = (same && q_img) ? IMG_START : rows;
            for (int j = 0; j < jmax; ++j) {
                bool vis;
                if (same) vis = true;  // jmax already enforces img->img rule
                else      vis = (j < JOINT_START) || ((j > PROPRIO) && !q_joint);
                if (vis) {
                    const float4* kr = (const float4*)(Kl + j * DHEAD);
                    float s = 0.f;
                    #pragma unroll
                    for (int i = 0; i < 8; ++i) {
                        float4 kk = kr[i];
                        s += qr[i].x * kk.x + qr[i].y * kk.y
                           + qr[i].z * kk.z + qr[i].w * kk.w;
                    }
                    // scores are O(1); no max-subtraction needed in fp32
                    float e = __expf(s * scale);
                    l += e;
                    const float4* vr = (const float4*)(Vl + j * DHEAD);
                    #pragma unroll
                    for (int i = 0; i < 8; ++i) {
                        float4 vv = vr[i];
                        acc[i].x += e * vv.x;
                        acc[i].y += e * vv.y;
                        acc[i].z += e * vv.z;
                        acc[i].w += e * vv.w;
                    }
                }
            }
        }
        __syncthreads();   // protect LDS before next block's staging
    }

    if (active) {
        const float inv = 1.f / l;
        float* op = out + base + (size_t)(t * FPT + qm) * DHEAD;
        #pragma unroll
        for (int i = 0; i < 8; ++i) {
            float4 r = acc[i];
            r.x *= inv; r.y *= inv; r.z *= inv; r.w *= inv;
            ((float4*)op)[i] = r;
        }
    }
}

extern "C" void kernel_launch(void* const* d_in, const int* in_sizes, int n_in,
                              void* d_out, int out_size, void* d_ws, size_t ws_size,
                              hipStream_t stream) {
    const float* q = (const float*)d_in[0];
    const float* k = (const float*)d_in[1];
    const float* v = (const float*)d_in[2];
    float* out = (float*)d_out;

    const int bh_count = in_sizes[0] / (SEQ * DHEAD);   // B*H = 24
    dim3 grid(NT, bh_count);
    dim3 block(256);
    eye_attn_kernel<<<grid, block, 0, stream>>>(q, k, v, out);
}